// Round 11
// baseline (97.716 us; speedup 1.0000x reference)
//
#include <hip/hip_runtime.h>
#include <math.h>

#define NROWS 4096
#define NHALF 2048
#define DDIM  256
#define INV_T 2.0f   // 1/TEMP, TEMP=0.5

typedef __attribute__((ext_vector_type(8))) __bf16 bf16x8;
typedef __attribute__((ext_vector_type(4))) float  f32x4;

__device__ __forceinline__ unsigned short f2bf(float f) {
  unsigned u = __float_as_uint(f);
  u += 0x7FFF + ((u >> 16) & 1);          // round-to-nearest-even
  return (unsigned short)(u >> 16);
}

// ---------------------------------------------------------------------------
// Kernel 1: row-normalize in fp32, emit bf16 rows; zero accumulators.
// 4 rows per 256-thread block (1 wave per row).
// ---------------------------------------------------------------------------
__global__ __launch_bounds__(256) void knorm(const float* __restrict__ xi,
                                             const float* __restrict__ xj,
                                             unsigned short* __restrict__ z,
                                             float* __restrict__ rowsum,
                                             float* __restrict__ pos) {
  const int row  = blockIdx.x * 4 + (threadIdx.x >> 6);
  const int lane = threadIdx.x & 63;       // 64 lanes x float4 = 256
  const float* src = (row < NHALF) ? (xi + (size_t)row * DDIM)
                                   : (xj + (size_t)(row - NHALF) * DDIM);
  float4 v = reinterpret_cast<const float4*>(src)[lane];
  float ss = v.x*v.x + v.y*v.y + v.z*v.z + v.w*v.w;
  #pragma unroll
  for (int off = 1; off < 64; off <<= 1) ss += __shfl_xor(ss, off);
  const float scale = 1.0f / fmaxf(sqrtf(ss), 1e-12f);
  ushort4 o;
  o.x = f2bf(v.x * scale); o.y = f2bf(v.y * scale);
  o.z = f2bf(v.z * scale); o.w = f2bf(v.w * scale);
  reinterpret_cast<ushort4*>(z + (size_t)row * DDIM)[lane] = o;
  if (lane == 0) { rowsum[row] = 0.0f; pos[row] = 0.0f; }
}

// ---------------------------------------------------------------------------
// Kernel 2: symmetric bf16 MFMA Gram, upper-triangle tiles (bj >= bi),
// NO LDS: z (2 MB) is L2/L3-resident, so fragments load straight from
// global (16B ds-free loads; lanes g=0..3 share one 128B line per row).
// No barriers, no staging latency chain; 4 blocks/CU (VGPR-bound).
// 128x128 tile, 4 waves (2x2), each 64x64 = 4x4 frags of 16x16x32.
// Off-diagonal tiles scatter exp-sums to BOTH row and col ranges.
// ---------------------------------------------------------------------------
__global__ __launch_bounds__(256, 4) void ksim(const unsigned short* __restrict__ z,
                                               float* __restrict__ rowsum,
                                               float* __restrict__ pos) {
  if (blockIdx.x < blockIdx.y) return;     // lower triangle: mirrored, skip

  const int t  = threadIdx.x;
  const int w  = t >> 6;                   // wave 0..3
  const int l  = t & 63;
  const int wm = w >> 1, wn = w & 1;       // 2x2 wave grid
  const int i0 = blockIdx.y * 128;
  const int j0 = blockIdx.x * 128;

  const int li = l & 15;                   // frag row-within-16 (A/B), col lane (C)
  const int g  = l >> 4;                   // k-octet 0..3

  // Per-m/n fragment row base pointers; kb advances via offset immediate.
  const unsigned short* arow[4];
  const unsigned short* brow[4];
  #pragma unroll
  for (int m = 0; m < 4; ++m)
    arow[m] = z + (size_t)(i0 + wm * 64 + m * 16 + li) * DDIM + g * 8;
  #pragma unroll
  for (int n = 0; n < 4; ++n)
    brow[n] = z + (size_t)(j0 + wn * 64 + n * 16 + li) * DDIM + g * 8;

  f32x4 acc[4][4];
  #pragma unroll
  for (int m = 0; m < 4; ++m)
    #pragma unroll
    for (int n = 0; n < 4; ++n) acc[m][n] = (f32x4)0.0f;

  #pragma unroll
  for (int kb = 0; kb < 8; ++kb) {         // K = 8 x 32, frag k = kb*32 + g*8
    bf16x8 af[4], bfr[4];
    #pragma unroll
    for (int m = 0; m < 4; ++m)
      af[m] = *(const bf16x8*)(arow[m] + kb * 32);
    #pragma unroll
    for (int n = 0; n < 4; ++n)
      bfr[n] = *(const bf16x8*)(brow[n] + kb * 32);
    #pragma unroll
    for (int m = 0; m < 4; ++m)
      #pragma unroll
      for (int n = 0; n < 4; ++n)
        acc[m][n] = __builtin_amdgcn_mfma_f32_16x16x32_bf16(
            af[m], bfr[n], acc[m][n], 0, 0, 0);
  }

  // Epilogue: C/D map col=lane&15, row=(lane>>4)*4+reg.
  // Row side (all tiles) + column side (off-diagonal tiles; sim symmetric).
  float ces[4] = {0.f, 0.f, 0.f, 0.f};     // per-col exp sums (this wave's rows)
  float cps[4] = {0.f, 0.f, 0.f, 0.f};     // per-col positive sums
  #pragma unroll
  for (int m = 0; m < 4; ++m) {
    #pragma unroll
    for (int r = 0; r < 4; ++r) {
      const int ig   = i0 + wm * 64 + m * 16 + g * 4 + r;
      const int ipos = (ig + NHALF) & (NROWS - 1);
      float es = 0.0f, ps = 0.0f;
      #pragma unroll
      for (int n = 0; n < 4; ++n) {
        const int jg = j0 + wn * 64 + n * 16 + li;
        const float sv = acc[m][n][r];
        const float e  = __expf(sv * INV_T);
        const float pv = (jg == ipos) ? sv : 0.0f;  // self-inverse predicate
        es += (jg != ig) ? e : 0.0f;       // exclude self (diag tiles only)
        ps += pv;
        ces[n] += e;                       // col side: no diag on off-diag tiles
        cps[n] += pv;
      }
      #pragma unroll
      for (int off = 1; off < 16; off <<= 1) {
        es += __shfl_xor(es, off);
        ps += __shfl_xor(ps, off);
      }
      if (li == 0) {
        atomicAdd(&rowsum[ig], es);
        atomicAdd(&pos[ig], ps);
      }
    }
  }
  if (i0 != j0) {                          // mirror into column rows
    #pragma unroll
    for (int n = 0; n < 4; ++n) {
      float ce = ces[n], cp = cps[n];
      ce += __shfl_xor(ce, 16); cp += __shfl_xor(cp, 16);
      ce += __shfl_xor(ce, 32); cp += __shfl_xor(cp, 32);
      if (l < 16) {                        // g == 0 lanes own 16 cols
        const int jg = j0 + wn * 64 + n * 16 + li;
        atomicAdd(&rowsum[jg], ce);
        atomicAdd(&pos[jg], cp);
      }
    }
  }
}

// ---------------------------------------------------------------------------
// Kernel 3: loss_i = log(denom_i) - pos_i/T ; out = mean.
// ---------------------------------------------------------------------------
__global__ __launch_bounds__(1024) void kfinal(const float* __restrict__ rowsum,
                                               const float* __restrict__ pos,
                                               float* __restrict__ out) {
  __shared__ float red[16];
  const int t = threadIdx.x;
  float acc = 0.0f;
  for (int i = t; i < NROWS; i += 1024)
    acc += logf(rowsum[i]) - INV_T * pos[i];
  #pragma unroll
  for (int off = 32; off > 0; off >>= 1) acc += __shfl_down(acc, off);
  if ((t & 63) == 0) red[t >> 6] = acc;
  __syncthreads();
  if (t < 64) {
    float v = (t < 16) ? red[t] : 0.0f;
    #pragma unroll
    for (int off = 8; off > 0; off >>= 1) v += __shfl_down(v, off);
    if (t == 0) out[0] = v * (1.0f / NROWS);
  }
}

// ---------------------------------------------------------------------------
extern "C" void kernel_launch(void* const* d_in, const int* in_sizes, int n_in,
                              void* d_out, int out_size, void* d_ws, size_t ws_size,
                              hipStream_t stream) {
  const float* xi = (const float*)d_in[0];
  const float* xj = (const float*)d_in[1];
  float* out = (float*)d_out;

  unsigned short* z = (unsigned short*)d_ws;                 // [4096][256] bf16 = 2 MB
  float* rowsum = (float*)((char*)d_ws + (size_t)NROWS * DDIM * 2);
  float* pos    = rowsum + NROWS;

  knorm<<<NROWS / 4, 256, 0, stream>>>(xi, xj, z, rowsum, pos);
  dim3 grid(NROWS / 128, NROWS / 128);                       // 32 x 32, upper-tri active
  ksim<<<grid, 256, 0, stream>>>(z, rowsum, pos);
  kfinal<<<1, 1024, 0, stream>>>(rowsum, pos, out);
}

// Round 12
// 80.875 us; speedup vs baseline: 1.2082x; 1.2082x over previous
//
#include <hip/hip_runtime.h>
#include <math.h>

#define NROWS 4096
#define NHALF 2048
#define DDIM  256
#define INV_T 2.0f   // 1/TEMP, TEMP=0.5

typedef __attribute__((ext_vector_type(8))) __bf16 bf16x8;
typedef __attribute__((ext_vector_type(4))) float  f32x4;

__device__ __forceinline__ unsigned short f2bf(float f) {
  unsigned u = __float_as_uint(f);
  u += 0x7FFF + ((u >> 16) & 1);          // round-to-nearest-even
  return (unsigned short)(u >> 16);
}

__device__ __forceinline__ void gload_lds16(const void* g, void* lds) {
  __builtin_amdgcn_global_load_lds(
      (const __attribute__((address_space(1))) void*)g,
      (__attribute__((address_space(3))) void*)lds, 16, 0, 0);
}

// ---------------------------------------------------------------------------
// Kernel 1: row-normalize in fp32, emit bf16 rows; zero accumulators.
// (measured-good 4096x64 config)
// ---------------------------------------------------------------------------
__global__ __launch_bounds__(64) void knorm(const float* __restrict__ xi,
                                            const float* __restrict__ xj,
                                            unsigned short* __restrict__ z,
                                            float* __restrict__ rowsum,
                                            float* __restrict__ pos) {
  const int row  = blockIdx.x;
  const int lane = threadIdx.x;            // 64 lanes x float4 = 256
  const float* src = (row < NHALF) ? (xi + (size_t)row * DDIM)
                                   : (xj + (size_t)(row - NHALF) * DDIM);
  float4 v = reinterpret_cast<const float4*>(src)[lane];
  float ss = v.x*v.x + v.y*v.y + v.z*v.z + v.w*v.w;
  #pragma unroll
  for (int off = 1; off < 64; off <<= 1) ss += __shfl_xor(ss, off);
  const float scale = 1.0f / fmaxf(sqrtf(ss), 1e-12f);
  ushort4 o;
  o.x = f2bf(v.x * scale); o.y = f2bf(v.y * scale);
  o.z = f2bf(v.z * scale); o.w = f2bf(v.w * scale);
  reinterpret_cast<ushort4*>(z + (size_t)row * DDIM)[lane] = o;
  if (lane == 0) { rowsum[row] = 0.0f; pos[row] = 0.0f; }
}

// ---------------------------------------------------------------------------
// Kernel 2: symmetric bf16 MFMA Gram, upper-triangle tiles (bj >= bi),
// SINGLE-buffered 32 KB LDS (4 blocks/CU) — all 528 active blocks
// co-resident in one wave of blocks. 128x128 tile, 4 waves (2x2),
// each 64x64 = 4x4 frags of 16x16x32. 16B-chunk XOR swizzle:
// linear global_load_lds dest + inverse-swizzled global src + swizzled read.
// Off-diagonal tiles scatter exp-sums to BOTH row and col ranges.
// ---------------------------------------------------------------------------
__global__ __launch_bounds__(256, 4) void ksim(const unsigned short* __restrict__ z,
                                               float* __restrict__ rowsum,
                                               float* __restrict__ pos) {
  if (blockIdx.x < blockIdx.y) return;     // lower triangle: mirrored, skip

  __shared__ __align__(16) unsigned short As[128 * 64];   // 16 KB
  __shared__ __align__(16) unsigned short Bs[128 * 64];   // 16 KB

  const int t  = threadIdx.x;
  const int w  = t >> 6;                  // wave 0..3
  const int l  = t & 63;
  const int wm = w >> 1, wn = w & 1;      // 2x2 wave grid
  const int i0 = blockIdx.y * 128;
  const int j0 = blockIdx.x * 128;

  const char* zb = (const char*)z;        // row stride 512 B
  char* Ab = (char*)As;
  char* Bb = (char*)Bs;

  // staging lane constants: one inst = 8 rows x 128B; lane l -> row l>>3,
  // lds chunk l&7; global src chunk = (l&7) ^ (row&7) = (l&7) ^ (l>>3)
  const int srow   = l >> 3;
  const int schunk = ((l & 7) ^ (l >> 3)) * 16;

  const int li = l & 15;                  // frag col lane
  const int g  = l >> 4;                  // k-group 0..3
  const int sw = l & 7;                   // row&7 for all frag rows

  f32x4 acc[4][4];
  #pragma unroll
  for (int m = 0; m < 4; ++m)
    #pragma unroll
    for (int n = 0; n < 4; ++n) acc[m][n] = (f32x4)0.0f;

  for (int kc = 0; kc < 4; ++kc) {        // K = 4 x 64
    __syncthreads();                      // prev-iter LDS reads done
    #pragma unroll
    for (int p = 0; p < 4; ++p) {
      const int r0 = w * 32 + p * 8;      // this wave's 8-row slab
      gload_lds16(zb + (size_t)(i0 + r0 + srow) * 512 + kc * 128 + schunk,
                  Ab + r0 * 128);
      gload_lds16(zb + (size_t)(j0 + r0 + srow) * 512 + kc * 128 + schunk,
                  Bb + r0 * 128);
    }
    __syncthreads();                      // drains vmcnt (global_load_lds)

    #pragma unroll
    for (int s = 0; s < 2; ++s) {         // two K=32 slices per stage
      const int coff = (((s * 4 + g) ^ sw) * 16);
      bf16x8 af[4], bfr[4];
      #pragma unroll
      for (int m = 0; m < 4; ++m)
        af[m] = *(const bf16x8*)(Ab + (wm * 64 + m * 16 + li) * 128 + coff);
      #pragma unroll
      for (int n = 0; n < 4; ++n)
        bfr[n] = *(const bf16x8*)(Bb + (wn * 64 + n * 16 + li) * 128 + coff);
      #pragma unroll
      for (int m = 0; m < 4; ++m)
        #pragma unroll
        for (int n = 0; n < 4; ++n)
          acc[m][n] = __builtin_amdgcn_mfma_f32_16x16x32_bf16(
              af[m], bfr[n], acc[m][n], 0, 0, 0);
    }
  }

  // Epilogue: C/D map col=lane&15, row=(lane>>4)*4+reg.
  // Row side (all tiles) + column side (off-diagonal tiles; sim symmetric).
  float ces[4] = {0.f, 0.f, 0.f, 0.f};    // per-col exp sums (this wave's rows)
  float cps[4] = {0.f, 0.f, 0.f, 0.f};    // per-col positive sums
  #pragma unroll
  for (int m = 0; m < 4; ++m) {
    #pragma unroll
    for (int r = 0; r < 4; ++r) {
      const int ig   = i0 + wm * 64 + m * 16 + g * 4 + r;
      const int ipos = (ig + NHALF) & (NROWS - 1);
      float es = 0.0f, ps = 0.0f;
      #pragma unroll
      for (int n = 0; n < 4; ++n) {
        const int jg = j0 + wn * 64 + n * 16 + li;
        const float sv = acc[m][n][r];
        const float e  = __expf(sv * INV_T);
        const float pv = (jg == ipos) ? sv : 0.0f;  // self-inverse predicate
        es += (jg != ig) ? e : 0.0f;      // exclude self (diag tiles only)
        ps += pv;
        ces[n] += e;                      // col side: no diag on off-diag tiles
        cps[n] += pv;
      }
      #pragma unroll
      for (int off = 1; off < 16; off <<= 1) {
        es += __shfl_xor(es, off);
        ps += __shfl_xor(ps, off);
      }
      if (li == 0) {
        atomicAdd(&rowsum[ig], es);
        atomicAdd(&pos[ig], ps);
      }
    }
  }
  if (i0 != j0) {                         // mirror into column rows
    #pragma unroll
    for (int n = 0; n < 4; ++n) {
      float ce = ces[n], cp = cps[n];
      ce += __shfl_xor(ce, 16); cp += __shfl_xor(cp, 16);
      ce += __shfl_xor(ce, 32); cp += __shfl_xor(cp, 32);
      if (l < 16) {                       // g == 0 lanes own 16 cols
        const int jg = j0 + wn * 64 + n * 16 + li;
        atomicAdd(&rowsum[jg], ce);
        atomicAdd(&pos[jg], cp);
      }
    }
  }
}

// ---------------------------------------------------------------------------
// Kernel 3: loss_i = log(denom_i) - pos_i/T ; out = mean.
// ---------------------------------------------------------------------------
__global__ __launch_bounds__(1024) void kfinal(const float* __restrict__ rowsum,
                                               const float* __restrict__ pos,
                                               float* __restrict__ out) {
  __shared__ float red[16];
  const int t = threadIdx.x;
  float acc = 0.0f;
  for (int i = t; i < NROWS; i += 1024)
    acc += logf(rowsum[i]) - INV_T * pos[i];
  #pragma unroll
  for (int off = 32; off > 0; off >>= 1) acc += __shfl_down(acc, off);
  if ((t & 63) == 0) red[t >> 6] = acc;
  __syncthreads();
  if (t < 64) {
    float v = (t < 16) ? red[t] : 0.0f;
    #pragma unroll
    for (int off = 8; off > 0; off >>= 1) v += __shfl_down(v, off);
    if (t == 0) out[0] = v * (1.0f / NROWS);
  }
}

// ---------------------------------------------------------------------------
extern "C" void kernel_launch(void* const* d_in, const int* in_sizes, int n_in,
                              void* d_out, int out_size, void* d_ws, size_t ws_size,
                              hipStream_t stream) {
  const float* xi = (const float*)d_in[0];
  const float* xj = (const float*)d_in[1];
  float* out = (float*)d_out;

  unsigned short* z = (unsigned short*)d_ws;                 // [4096][256] bf16 = 2 MB
  float* rowsum = (float*)((char*)d_ws + (size_t)NROWS * DDIM * 2);
  float* pos    = rowsum + NROWS;

  knorm<<<NROWS, 64, 0, stream>>>(xi, xj, z, rowsum, pos);
  dim3 grid(NROWS / 128, NROWS / 128);                       // 32 x 32, upper-tri active
  ksim<<<grid, 256, 0, stream>>>(z, rowsum, pos);
  kfinal<<<1, 1024, 0, stream>>>(rowsum, pos, out);
}